// Round 9
// baseline (39.942 us; speedup 1.0000x reference)
//
#include <hip/hip_runtime.h>

// Deformable unfold: x (4,64,128,128) f32, offset (4,18,128,128) f32
// out (4, 64*9, 128*128) f32;  out[b][c*9+k][s] = bilinear(x[b][c], py, px)
//
// v9 = v8 with ONE change: regular stores instead of __builtin_nontemporal_store.
// A/B isolating the NT hint. Theory: NT bypasses L2 write-combining; with
// ~9K concurrent 2KB-granular output streams, L2 aggregation into long HBM
// bursts is what lets the fill kernel hit 7.1 TB/s; NT may be capping us at
// ~4.5-4.9 TB/s effective.
//  - TPB 512, 4-row s-tiles (NR=20), channel split 4 (16 ch/block)
//  - grid 512 = 2 blocks/CU, 16 waves/CU
//  - no VGPR clamp (v7 lesson), drain-free barriers, PITCH=130,
//    conflict-free ds_writes, register prefetch pipeline, ballot fall flag

#define BB 4
#define CC 64
#define HH 128
#define WW 128
#define KK 9
#define HW (HH * WW)    // 16384
#define TROWS 4         // output rows per tile
#define NR 20           // staged rows (4 output rows + margin)
#define PITCH 130       // padded row pitch in float2
#define CGB 16          // channels per block
#define NGB 4           // channel groups
#define TPB 512
#define NF4 (NR * 64)   // 1280 float4s per staged channel-pair tile

// post-write barrier: LDS visibility only, globals stay in flight
#define LDS_BARRIER()                                         \
    do {                                                      \
        asm volatile("s_waitcnt lgkmcnt(0)" ::: "memory");    \
        __builtin_amdgcn_s_barrier();                         \
        asm volatile("" ::: "memory");                        \
    } while (0)

// top-of-loop barrier: no waitcnt (prev-tile reads already consumed)
#define BARE_BARRIER()                                        \
    do {                                                      \
        asm volatile("" ::: "memory");                        \
        __builtin_amdgcn_s_barrier();                         \
        asm volatile("" ::: "memory");                        \
    } while (0)

__global__ __launch_bounds__(TPB) void deform_unfold_v9(
    const float* __restrict__ x, const float* __restrict__ off,
    float* __restrict__ out)
{
    __shared__ float2 tile[NR * PITCH];   // 20.8 KB
    __shared__ int wf[TPB / 64];

    const int tid = threadIdx.x;
    const int bid = blockIdx.x;
    const int g = bid & (NGB - 1);        // channel group (fastest: shares offsets)
    const int t = (bid >> 2) & 31;        // 4-row tile index
    const int b = bid >> 7;               // batch

    const int s  = t * 512 + tid;
    const int wo = s & (WW - 1);
    const int ho = s >> 7;
    const int r0 = min(max(TROWS * t - 8, 0), HH - NR);

    const int c0g = g * CGB;
    const float* xb = x + ((size_t)b * CC + c0g) * HW;
    float* ob = out + (((size_t)b * CC + c0g) * KK) * HW + s;

    // ---- offsets first (FIFO-early) ----
    float oyv[KK], oxv[KK];
    {
        const float* offb = off + ((size_t)b * (2 * KK)) * HW + s;
        #pragma unroll
        for (int k = 0; k < KK; ++k) {
            oyv[k] = offb[(size_t)(2 * k) * HW];
            oxv[k] = offb[(size_t)(2 * k + 1) * HW];
        }
    }
    // ---- x prologue for cp=0 (guarded: 1280 float2-pairs over 512 threads)
    float2 ca[3], cb[3];
    {
        const float2* A2 = (const float2*)(xb + (size_t)r0 * WW);
        const float2* B2 = (const float2*)(xb + HW + (size_t)r0 * WW);
        #pragma unroll
        for (int j = 0; j < 3; ++j) {
            int id = tid + TPB * j;
            if (id < NF4) {
                int e = (id >> 6) * 64 + (id & 63);
                ca[j] = A2[e]; cb[j] = B2[e];
            }
        }
    }

    // ---- per-(s,k) descriptors ----
    float u0[KK], u1[KK], t0w[KK], t1w[KK];
    int aAB[KK];
    int myfall = 0;
    #pragma unroll
    for (int k = 0; k < KK; ++k) {
        int ky = k / 3, kx = k - ky * 3;
        float py = oyv[k] + (float)(ho - 1 + ky);
        float px = oxv[k] + (float)(wo - 1 + kx);
        float y0f = floorf(py), x0f = floorf(px);
        float wy1 = py - y0f, wx1 = px - x0f;
        float wy0 = 1.f - wy1, wx0 = 1.f - wx1;
        int y0 = (int)y0f, x0 = (int)x0f;
        int y1 = y0 + 1, x1 = x0 + 1;
        bool vy0 = (y0 >= 0) && (y0 < HH), vy1 = (y1 >= 0) && (y1 < HH);
        bool vx0 = (x0 >= 0) && (x0 < WW), vx1 = (x1 >= 0) && (x1 < WW);
        int y0c = min(max(y0, 0), HH - 1), y1c = min(max(y1, 0), HH - 1);
        int xa  = min(max(x0, 0), WW - 2);          // pair base col: xa, xa+1
        int i0  = min(max(x0, 0), WW - 1) - xa;     // which pair elem is x0c
        int i1  = min(max(x1, 0), WW - 1) - xa;     // which pair elem is x1c
        float w00 = wy0 * wx0 * ((vy0 && vx0) ? 1.f : 0.f);
        float w01 = wy0 * wx1 * ((vy0 && vx1) ? 1.f : 0.f);
        float w10 = wy1 * wx0 * ((vy1 && vx0) ? 1.f : 0.f);
        float w11 = wy1 * wx1 * ((vy1 && vx1) ? 1.f : 0.f);
        u0[k]  = (i0 == 0 ? w00 : 0.f) + (i1 == 0 ? w01 : 0.f);
        u1[k]  = (i0 == 1 ? w00 : 0.f) + (i1 == 1 ? w01 : 0.f);
        t0w[k] = (i0 == 0 ? w10 : 0.f) + (i1 == 0 ? w11 : 0.f);
        t1w[k] = (i0 == 1 ? w10 : 0.f) + (i1 == 1 ? w11 : 0.f);
        int rA = y0c - r0, rB = y1c - r0;
        myfall |= ((unsigned)rA >= NR) | ((unsigned)rB >= NR);
        rA = min(max(rA, 0), NR - 1);
        rB = min(max(rB, 0), NR - 1);
        aAB[k] = (rA * PITCH + xa) | ((rB * PITCH + xa) << 16);
    }
    // block-uniform fall flag: ballot + per-wave flags + ONE lgkm barrier
    unsigned long long bal = __ballot(myfall != 0);
    if ((tid & 63) == 0) wf[tid >> 6] = (bal != 0) ? 1 : 0;
    LDS_BARRIER();
    int fr = 0;
    #pragma unroll
    for (int w = 0; w < TPB / 64; ++w) fr |= wf[w];
    const bool fall = (fr != 0);

    if (!fall) {
        #pragma unroll
        for (int cp = 0; cp < CGB / 2; ++cp) {
            if (cp > 0) BARE_BARRIER();
            // conflict-free staging write: lane-uniform row, 16B lane stride
            float4* wt = (float4*)tile;
            #pragma unroll
            for (int j = 0; j < 3; ++j) {
                int id = tid + TPB * j;
                if (id < NF4)
                    wt[(id >> 6) * (PITCH / 2) + (id & 63)] =
                        make_float4(ca[j].x, cb[j].x, ca[j].y, cb[j].y);
            }
            // prefetch next channel pair (in flight across barrier + compute)
            if (cp + 1 < CGB / 2) {
                const float2* A2 = (const float2*)(xb + (size_t)(2 * cp + 2) * HW + (size_t)r0 * WW);
                const float2* B2 = (const float2*)(xb + (size_t)(2 * cp + 3) * HW + (size_t)r0 * WW);
                #pragma unroll
                for (int j = 0; j < 3; ++j) {
                    int id = tid + TPB * j;
                    if (id < NF4) {
                        int e = (id >> 6) * 64 + (id & 63);
                        ca[j] = A2[e]; cb[j] = B2[e];
                    }
                }
            }
            LDS_BARRIER();   // lgkm only: stores/prefetch stay in flight
            const float2* tl = tile;
            float* o = ob + (size_t)(2 * cp) * KK * HW;
            #pragma unroll
            for (int k = 0; k < KK; ++k) {
                int aA = aAB[k] & 0xffff, aB = aAB[k] >> 16;
                float2 p00 = tl[aA], p01 = tl[aA + 1];
                float2 p10 = tl[aB], p11 = tl[aB + 1];
                float vx_ = p00.x * u0[k] + p01.x * u1[k] + p10.x * t0w[k] + p11.x * t1w[k];
                float vy_ = p00.y * u0[k] + p01.y * u1[k] + p10.y * t0w[k] + p11.y * t1w[k];
                o[(size_t)k * HW] = vx_;            // regular store (A/B vs NT)
                o[(size_t)(KK + k) * HW] = vy_;     // regular store (A/B vs NT)
            }
        }
    } else {
        // exact slow path: direct global gather for the whole block (rare)
        #pragma unroll 1
        for (int k = 0; k < KK; ++k) {
            int ky = k / 3, kx = k - ky * 3;
            float py = oyv[k] + (float)(ho - 1 + ky);
            float px = oxv[k] + (float)(wo - 1 + kx);
            float y0f = floorf(py), x0f = floorf(px);
            float wy1 = py - y0f, wx1 = px - x0f;
            float wy0 = 1.f - wy1, wx0 = 1.f - wx1;
            int y0 = (int)y0f, x0 = (int)x0f;
            int y1 = y0 + 1, x1 = x0 + 1;
            bool vy0 = (y0 >= 0) && (y0 < HH), vy1 = (y1 >= 0) && (y1 < HH);
            bool vx0 = (x0 >= 0) && (x0 < WW), vx1 = (x1 >= 0) && (x1 < WW);
            int y0c = min(max(y0, 0), HH - 1), y1c = min(max(y1, 0), HH - 1);
            int x0c = min(max(x0, 0), WW - 1), x1c = min(max(x1, 0), WW - 1);
            float w00 = wy0 * wx0 * ((vy0 && vx0) ? 1.f : 0.f);
            float w01 = wy0 * wx1 * ((vy0 && vx1) ? 1.f : 0.f);
            float w10 = wy1 * wx0 * ((vy1 && vx0) ? 1.f : 0.f);
            float w11 = wy1 * wx1 * ((vy1 && vx1) ? 1.f : 0.f);
            int o00 = y0c * WW + x0c, o01 = y0c * WW + x1c;
            int o10 = y1c * WW + x0c, o11 = y1c * WW + x1c;
            #pragma unroll 1
            for (int c = 0; c < CGB; ++c) {
                const float* xc = xb + (size_t)c * HW;
                (ob + (size_t)c * KK * HW)[(size_t)k * HW] =
                    xc[o00] * w00 + xc[o01] * w01 + xc[o10] * w10 + xc[o11] * w11;
            }
        }
    }
}

extern "C" void kernel_launch(void* const* d_in, const int* in_sizes, int n_in,
                              void* d_out, int out_size, void* d_ws, size_t ws_size,
                              hipStream_t stream) {
    const float* x   = (const float*)d_in[0];
    const float* off = (const float*)d_in[1];
    float* out = (float*)d_out;

    int blocks = BB * 32 * NGB;   // 512 = 2 blocks/CU
    deform_unfold_v9<<<blocks, TPB, 0, stream>>>(x, off, out);
}

// Round 10
// 38.040 us; speedup vs baseline: 1.0500x; 1.0500x over previous
//
#include <hip/hip_runtime.h>

// Deformable unfold: x (4,64,128,128) f32, offset (4,18,128,128) f32
// out (4, 64*9, 128*128) f32;  out[b][c*9+k][s] = bilinear(x[b][c], py, px)
//
// FINAL REVERT: exact round-3 kernel (v3) — the empirical best (37.9 us).
// Plateau ledger (all within ±1us of 38.9): dbuf(r4), drain-free barriers(r5),
// pitch padding(r5), XCD swizzle(r6/7), TPB/occupancy/redundancy(r8), NT A/B(r9).
// Structure: block = (b, 2-row s-tile of 256, 8-channel group); 16 rows x 128
// cols of 2 channels interleaved as float2 in 16KB LDS; conflict-free staging
// writes; register prefetch of next channel pair; NT dword stores.

#define BB 4
#define CC 64
#define HH 128
#define WW 128
#define KK 9
#define HW (HH * WW)    // 16384
#define NR 16           // staged rows per tile
#define CG 8            // channels per block
#define NG (CC / CG)    // 8 channel groups
#define TPB 256

__global__ __launch_bounds__(TPB, 4) void deform_unfold_lds(
    const float* __restrict__ x, const float* __restrict__ off,
    float* __restrict__ out)
{
    __shared__ float2 tile[NR * WW];   // 16 KB, .x = ch c, .y = ch c+1
    __shared__ int anyfall;

    const int tid = threadIdx.x;
    const int bid = blockIdx.x;
    const int g = bid & (NG - 1);
    const int t = (bid >> 3) & 63;
    const int b = bid >> 9;

    const int s  = t * TPB + tid;
    const int wo = s & (WW - 1);
    const int ho = s >> 7;
    const int r0 = min(max(2 * t - 6, 0), HH - NR);

    const int c0g = g * CG;
    const float* xb = x + ((size_t)b * CC + c0g) * HW;
    float* ob = out + (((size_t)b * CC + c0g) * KK) * HW + s;

    // ---- prologue: issue staging loads for cp=0 (latency hides under descriptors)
    float2 pa[4], pb[4];
    {
        const float2* A2 = (const float2*)(xb + (size_t)r0 * WW);
        const float2* B2 = (const float2*)(xb + HW + (size_t)r0 * WW);
        #pragma unroll
        for (int j = 0; j < 4; ++j) { pa[j] = A2[tid + 256 * j]; pb[j] = B2[tid + 256 * j]; }
    }

    if (tid == 0) anyfall = 0;
    __syncthreads();

    // ---- per-(s,k) descriptors ----
    float u0[KK], u1[KK], t0w[KK], t1w[KK];
    int aAB[KK];            // packed LDS element indices: aA | (aB<<16)
    int myfall = 0;
    #pragma unroll
    for (int k = 0; k < KK; ++k) {
        int ky = k / 3, kx = k - ky * 3;
        float oy = off[(((size_t)b * (2 * KK)) + 2 * k) * HW + s];
        float ox = off[(((size_t)b * (2 * KK)) + 2 * k + 1) * HW + s];
        float py = oy + (float)(ho - 1 + ky);
        float px = ox + (float)(wo - 1 + kx);
        float y0f = floorf(py), x0f = floorf(px);
        float wy1 = py - y0f, wx1 = px - x0f;
        float wy0 = 1.f - wy1, wx0 = 1.f - wx1;
        int y0 = (int)y0f, x0 = (int)x0f;
        int y1 = y0 + 1, x1 = x0 + 1;
        bool vy0 = (y0 >= 0) && (y0 < HH), vy1 = (y1 >= 0) && (y1 < HH);
        bool vx0 = (x0 >= 0) && (x0 < WW), vx1 = (x1 >= 0) && (x1 < WW);
        int y0c = min(max(y0, 0), HH - 1), y1c = min(max(y1, 0), HH - 1);
        int xa  = min(max(x0, 0), WW - 2);          // pair base col: xa, xa+1
        int i0  = min(max(x0, 0), WW - 1) - xa;     // which pair elem is x0c
        int i1  = min(max(x1, 0), WW - 1) - xa;     // which pair elem is x1c
        float w00 = wy0 * wx0 * ((vy0 && vx0) ? 1.f : 0.f);
        float w01 = wy0 * wx1 * ((vy0 && vx1) ? 1.f : 0.f);
        float w10 = wy1 * wx0 * ((vy1 && vx0) ? 1.f : 0.f);
        float w11 = wy1 * wx1 * ((vy1 && vx1) ? 1.f : 0.f);
        u0[k]  = (i0 == 0 ? w00 : 0.f) + (i1 == 0 ? w01 : 0.f);
        u1[k]  = (i0 == 1 ? w00 : 0.f) + (i1 == 1 ? w01 : 0.f);
        t0w[k] = (i0 == 0 ? w10 : 0.f) + (i1 == 0 ? w11 : 0.f);
        t1w[k] = (i0 == 1 ? w10 : 0.f) + (i1 == 1 ? w11 : 0.f);
        int rA = y0c - r0, rB = y1c - r0;
        myfall |= ((unsigned)rA >= NR) | ((unsigned)rB >= NR);
        rA = min(max(rA, 0), NR - 1);
        rB = min(max(rB, 0), NR - 1);
        aAB[k] = (rA * WW + xa) | ((rB * WW + xa) << 16);
    }
    if (myfall) atomicOr(&anyfall, 1);
    __syncthreads();
    const bool fall = (anyfall != 0);   // block-uniform

    if (!fall) {
        #pragma unroll
        for (int cp = 0; cp < CG / 2; ++cp) {
            // conflict-free staging write: 16B lane stride
            float4* wt = (float4*)tile;
            #pragma unroll
            for (int j = 0; j < 4; ++j)
                wt[tid + 256 * j] = make_float4(pa[j].x, pb[j].x, pa[j].y, pb[j].y);
            // prefetch next channel pair into regs (hides under compute)
            if (cp + 1 < CG / 2) {
                const float2* A2 = (const float2*)(xb + (size_t)(2 * cp + 2) * HW + (size_t)r0 * WW);
                const float2* B2 = (const float2*)(xb + (size_t)(2 * cp + 3) * HW + (size_t)r0 * WW);
                #pragma unroll
                for (int j = 0; j < 4; ++j) { pa[j] = A2[tid + 256 * j]; pb[j] = B2[tid + 256 * j]; }
            }
            __syncthreads();
            float* o = ob + (size_t)(2 * cp) * KK * HW;
            #pragma unroll
            for (int k = 0; k < KK; ++k) {
                int aA = aAB[k] & 0xffff, aB = aAB[k] >> 16;
                float2 p00 = tile[aA], p01 = tile[aA + 1];
                float2 p10 = tile[aB], p11 = tile[aB + 1];
                float vx_ = p00.x * u0[k] + p01.x * u1[k] + p10.x * t0w[k] + p11.x * t1w[k];
                float vy_ = p00.y * u0[k] + p01.y * u1[k] + p10.y * t0w[k] + p11.y * t1w[k];
                __builtin_nontemporal_store(vx_, o + (size_t)k * HW);
                __builtin_nontemporal_store(vy_, o + (size_t)(KK + k) * HW);
            }
            __syncthreads();
        }
    } else {
        // exact slow path: direct global gather for the whole block (rare)
        #pragma unroll 1
        for (int k = 0; k < KK; ++k) {
            int ky = k / 3, kx = k - ky * 3;
            float oy = off[(((size_t)b * (2 * KK)) + 2 * k) * HW + s];
            float ox = off[(((size_t)b * (2 * KK)) + 2 * k + 1) * HW + s];
            float py = oy + (float)(ho - 1 + ky);
            float px = ox + (float)(wo - 1 + kx);
            float y0f = floorf(py), x0f = floorf(px);
            float wy1 = py - y0f, wx1 = px - x0f;
            float wy0 = 1.f - wy1, wx0 = 1.f - wx1;
            int y0 = (int)y0f, x0 = (int)x0f;
            int y1 = y0 + 1, x1 = x0 + 1;
            bool vy0 = (y0 >= 0) && (y0 < HH), vy1 = (y1 >= 0) && (y1 < HH);
            bool vx0 = (x0 >= 0) && (x0 < WW), vx1 = (x1 >= 0) && (x1 < WW);
            int y0c = min(max(y0, 0), HH - 1), y1c = min(max(y1, 0), HH - 1);
            int x0c = min(max(x0, 0), WW - 1), x1c = min(max(x1, 0), WW - 1);
            float w00 = wy0 * wx0 * ((vy0 && vx0) ? 1.f : 0.f);
            float w01 = wy0 * wx1 * ((vy0 && vx1) ? 1.f : 0.f);
            float w10 = wy1 * wx0 * ((vy1 && vx0) ? 1.f : 0.f);
            float w11 = wy1 * wx1 * ((vy1 && vx1) ? 1.f : 0.f);
            int o00 = y0c * WW + x0c, o01 = y0c * WW + x1c;
            int o10 = y1c * WW + x0c, o11 = y1c * WW + x1c;
            #pragma unroll 1
            for (int c = 0; c < CG; ++c) {
                const float* xc = xb + (size_t)c * HW;
                (ob + (size_t)c * KK * HW)[(size_t)k * HW] =
                    xc[o00] * w00 + xc[o01] * w01 + xc[o10] * w10 + xc[o11] * w11;
            }
        }
    }
}

extern "C" void kernel_launch(void* const* d_in, const int* in_sizes, int n_in,
                              void* d_out, int out_size, void* d_ws, size_t ws_size,
                              hipStream_t stream) {
    const float* x   = (const float*)d_in[0];
    const float* off = (const float*)d_in[1];
    float* out = (float*)d_out;

    int blocks = BB * 64 * NG;   // 2048
    deform_unfold_lds<<<blocks, TPB, 0, stream>>>(x, off, out);
}